// Round 3
// baseline (113.319 us; speedup 1.0000x reference)
//
#include <hip/hip_runtime.h>
#include <hip/hip_bf16.h>

// Sizes (static, from reference)
#define NSUB 65536
#define NV0 10242
#define NV1 40962
#define NV2 163842
#define EPSV 1e-5f

// ---------------------------------------------------------------------------
// Zero the stats accumulators
__global__ void k_zero(float* p, int n) {
    int i = blockIdx.x * blockDim.x + threadIdx.x;
    if (i < n) p[i] = 0.f;
}

// ---------------------------------------------------------------------------
// y1[256] = sub_id[65536] . W_sub[o, :] + b_sub[o]
// one block per output, 256 threads, float4 vector loads
__global__ __launch_bounds__(256) void k_gemv1(const float* __restrict__ sub,
                                               const float* __restrict__ Ws,
                                               const float* __restrict__ bs,
                                               float* __restrict__ y1) {
    int o = blockIdx.x;
    const float* row = Ws + (size_t)o * NSUB;
    int t = threadIdx.x;
    float acc = 0.f;
    for (int i = t * 4; i < NSUB; i += 256 * 4) {
        float4 a = *(const float4*)(sub + i);
        float4 w = *(const float4*)(row + i);
        acc += a.x * w.x + a.y * w.y + a.z * w.z + a.w * w.w;
    }
#pragma unroll
    for (int off = 32; off > 0; off >>= 1) acc += __shfl_down(acc, off, 64);
    __shared__ float red[4];
    int wv = t >> 6, ln = t & 63;
    if (ln == 0) red[wv] = acc;
    __syncthreads();
    if (t == 0) y1[o] = red[0] + red[1] + red[2] + red[3] + bs[o];
}

// ---------------------------------------------------------------------------
// x0[o] = y1[0:256] . W_fc[o, :] + b_fc[o], o < 30726. One wave per output.
__global__ __launch_bounds__(256) void k_gemv2(const float* __restrict__ y1,
                                               const float* __restrict__ Wf,
                                               const float* __restrict__ bfc,
                                               float* __restrict__ x0) {
    int o = blockIdx.x * 4 + (threadIdx.x >> 6);
    int ln = threadIdx.x & 63;
    if (o >= 3 * NV0) return;
    const float* row = Wf + (size_t)o * 256;
    float4 w4 = *(const float4*)(row + ln * 4);
    float4 yv = *(const float4*)(y1 + ln * 4);
    float acc = w4.x * yv.x + w4.y * yv.y + w4.z * yv.z + w4.w * yv.w;
#pragma unroll
    for (int off = 32; off > 0; off >>= 1) acc += __shfl_down(acc, off, 64);
    if (ln == 0) x0[o] = acc + bfc[o];
}

// ---------------------------------------------------------------------------
// Per-channel sum and sum-of-squares of x [n, C] -> sums[0:C]=S1, sums[C:2C]=S2
template <int C>
__global__ __launch_bounds__(256) void k_stats(const float* __restrict__ x, int n,
                                               float* __restrict__ sums) {
    float s[C], q[C];
#pragma unroll
    for (int c = 0; c < C; ++c) { s[c] = 0.f; q[c] = 0.f; }
    for (int v = blockIdx.x * 256 + threadIdx.x; v < n; v += gridDim.x * 256) {
#pragma unroll
        for (int c = 0; c < C; ++c) {
            float t = x[(size_t)v * C + c];
            s[c] += t; q[c] += t * t;
        }
    }
#pragma unroll
    for (int c = 0; c < C; ++c) {
#pragma unroll
        for (int off = 32; off > 0; off >>= 1) {
            s[c] += __shfl_down(s[c], off, 64);
            q[c] += __shfl_down(q[c], off, 64);
        }
    }
    __shared__ float ls[4][2 * C];
    int wv = threadIdx.x >> 6, ln = threadIdx.x & 63;
    if (ln == 0) {
#pragma unroll
        for (int c = 0; c < C; ++c) { ls[wv][c] = s[c]; ls[wv][C + c] = q[c]; }
    }
    __syncthreads();
    if (threadIdx.x < 2 * C) {
        float t = ls[0][threadIdx.x] + ls[1][threadIdx.x] +
                  ls[2][threadIdx.x] + ls[3][threadIdx.x];
        atomicAdd(&sums[threadIdx.x], t);
    }
}

// ---------------------------------------------------------------------------
// upconv: xin [nIn,3] --bn,lrelu--> linear(3->21) viewed [nIn*7,3],
// then gather: v<nIn: u[top[v]]; else interleaved mean of u[down[2i]],u[down[2i+1]]
__global__ __launch_bounds__(256) void k_upconv(const float* __restrict__ xin, int nIn, int nOut,
                                                const float* __restrict__ sums,
                                                const float* __restrict__ g, const float* __restrict__ b,
                                                const float* __restrict__ W, const float* __restrict__ bias,
                                                const int* __restrict__ top, const int* __restrict__ down,
                                                float* __restrict__ xout) {
    __shared__ float sW[63], sB[21], sc[3], sh[3];
    int t = threadIdx.x;
    if (t < 63) sW[t] = W[t];
    if (t < 21) sB[t] = bias[t];
    if (t < 3) {
        float n = (float)nIn;
        float m = sums[t] / n;
        float var = sums[3 + t] / n - m * m;
        float rs = rsqrtf(var + EPSV);
        float scale = rs * g[t];
        sc[t] = scale;
        sh[t] = b[t] - m * scale;
    }
    __syncthreads();
    int v = blockIdx.x * 256 + t;
    if (v >= nOut) return;

    auto uval = [&](int idx, float* o3) {
        int src = idx / 7;
        int j = idx - src * 7;
        float a0 = xin[src * 3 + 0] * sc[0] + sh[0]; a0 = a0 > 0.f ? a0 : 0.2f * a0;
        float a1 = xin[src * 3 + 1] * sc[1] + sh[1]; a1 = a1 > 0.f ? a1 : 0.2f * a1;
        float a2 = xin[src * 3 + 2] * sc[2] + sh[2]; a2 = a2 > 0.f ? a2 : 0.2f * a2;
#pragma unroll
        for (int c = 0; c < 3; ++c) {
            int r = j * 3 + c;
            o3[c] = sB[r] + a0 * sW[r * 3 + 0] + a1 * sW[r * 3 + 1] + a2 * sW[r * 3 + 2];
        }
    };

    if (v < nIn) {
        float o3[3];
        uval(top[v], o3);
        xout[(size_t)v * 3 + 0] = o3[0];
        xout[(size_t)v * 3 + 1] = o3[1];
        xout[(size_t)v * 3 + 2] = o3[2];
    } else {
        int i = v - nIn;
        float a[3], bb[3];
        uval(down[2 * i], a);
        uval(down[2 * i + 1], bb);
        // x[down].reshape(-1, 3, 2).mean(2): interleaved pairing
        xout[(size_t)v * 3 + 0] = 0.5f * (a[0] + a[1]);
        xout[(size_t)v * 3 + 1] = 0.5f * (a[2] + bb[0]);
        xout[(size_t)v * 3 + 2] = 0.5f * (bb[1] + bb[2]);
    }
}

// ---------------------------------------------------------------------------
// one-ring conv: gather 7 neighbors of lrelu(bn(xin)), apply [COUT, 7*CIN] linear
template <int CIN, int COUT>
__global__ __launch_bounds__(256) void k_onering(const float* __restrict__ xin,
                                                 const float* __restrict__ sums, int n,
                                                 const float* __restrict__ g, const float* __restrict__ b,
                                                 const float* __restrict__ W, const float* __restrict__ bias,
                                                 const int* __restrict__ neigh,
                                                 float* __restrict__ out) {
    __shared__ float sW[COUT * 7 * CIN], sB[COUT], sc[CIN], sh[CIN];
    int t = threadIdx.x;
    for (int i = t; i < COUT * 7 * CIN; i += 256) sW[i] = W[i];
    if (t < COUT) sB[t] = bias[t];
    if (t < CIN) {
        float nn = (float)n;
        float m = sums[t] / nn;
        float var = sums[CIN + t] / nn - m * m;
        float rs = rsqrtf(var + EPSV);
        float scale = rs * g[t];
        sc[t] = scale;
        sh[t] = b[t] - m * scale;
    }
    __syncthreads();
    int v = blockIdx.x * 256 + t;
    if (v >= n) return;

    float acc[COUT];
#pragma unroll
    for (int c = 0; c < COUT; ++c) acc[c] = sB[c];
#pragma unroll
    for (int j = 0; j < 7; ++j) {
        int nb = neigh[v * 7 + j];
        float tv[CIN];
#pragma unroll
        for (int k = 0; k < CIN; ++k) {
            float x = xin[(size_t)nb * CIN + k] * sc[k] + sh[k];
            tv[k] = x > 0.f ? x : 0.2f * x;
        }
#pragma unroll
        for (int c = 0; c < COUT; ++c) {
            float a = acc[c];
#pragma unroll
            for (int k = 0; k < CIN; ++k) a += tv[k] * sW[c * 7 * CIN + j * CIN + k];
            acc[c] = a;
        }
    }
#pragma unroll
    for (int c = 0; c < COUT; ++c) out[(size_t)v * COUT + c] = acc[c];
}

// ---------------------------------------------------------------------------
extern "C" void kernel_launch(void* const* d_in, const int* in_sizes, int n_in,
                              void* d_out, int out_size, void* d_ws, size_t ws_size,
                              hipStream_t stream) {
    const float* sub_id = (const float*)d_in[0];
    const float* W_sub  = (const float*)d_in[1];
    const float* b_sub  = (const float*)d_in[2];
    const float* W_fc   = (const float*)d_in[3];
    const float* b_fc   = (const float*)d_in[4];
    const float* bn_u0g = (const float*)d_in[5];
    const float* bn_u0b = (const float*)d_in[6];
    const float* up0_W  = (const float*)d_in[7];
    const float* up0_b  = (const float*)d_in[8];
    const float* bn_u1g = (const float*)d_in[9];
    const float* bn_u1b = (const float*)d_in[10];
    const float* up1_W  = (const float*)d_in[11];
    const float* up1_b  = (const float*)d_in[12];
    const float* bn0g   = (const float*)d_in[13];
    const float* bn0b   = (const float*)d_in[14];
    const float* c0_W   = (const float*)d_in[15];
    const float* c0_b   = (const float*)d_in[16];
    const float* bn1g   = (const float*)d_in[17];
    const float* bn1b   = (const float*)d_in[18];
    const float* c1_W   = (const float*)d_in[19];
    const float* c1_b   = (const float*)d_in[20];
    const float* bn2g   = (const float*)d_in[21];
    const float* bn2b   = (const float*)d_in[22];
    const float* c2_W   = (const float*)d_in[23];
    const float* c2_b   = (const float*)d_in[24];
    const int* neigh  = (const int*)d_in[25];
    const int* top0   = (const int*)d_in[26];
    const int* down0  = (const int*)d_in[27];
    const int* top1   = (const int*)d_in[28];
    const int* down1  = (const int*)d_in[29];

    float* ws = (float*)d_ws;
    float* y1 = ws;                       // 256
    float* x0 = y1 + 256;                 // 30726
    float* xA = x0 + 30726;               // 122886
    float* xB = xA + 122886;              // 491526
    float* h0 = xB + 491526;              // 1310736
    float* h1 = h0 + 1310736;             // 1310736
    float* st = h1 + 1310736;             // 50 floats of stats accumulators
    float* st0 = st;        // x0 stats  [6]
    float* st1 = st + 6;    // xA stats  [6]
    float* st2 = st + 12;   // xB stats  [6]
    float* st3 = st + 18;   // h0 stats  [16]
    float* st4 = st + 34;   // h1 stats  [16]

    k_zero<<<1, 64, 0, stream>>>(st, 50);

    k_gemv1<<<256, 256, 0, stream>>>(sub_id, W_sub, b_sub, y1);
    k_gemv2<<<(3 * NV0 + 3) / 4, 256, 0, stream>>>(y1, W_fc, b_fc, x0);

    k_stats<3><<<64, 256, 0, stream>>>(x0, NV0, st0);
    k_upconv<<<(NV1 + 255) / 256, 256, 0, stream>>>(x0, NV0, NV1, st0,
                                                    bn_u0g, bn_u0b, up0_W, up0_b,
                                                    top0, down0, xA);
    k_stats<3><<<64, 256, 0, stream>>>(xA, NV1, st1);
    k_upconv<<<(NV2 + 255) / 256, 256, 0, stream>>>(xA, NV1, NV2, st1,
                                                    bn_u1g, bn_u1b, up1_W, up1_b,
                                                    top1, down1, xB);

    k_stats<3><<<64, 256, 0, stream>>>(xB, NV2, st2);
    k_onering<3, 8><<<(NV2 + 255) / 256, 256, 0, stream>>>(
        xB, st2, NV2, bn0g, bn0b, c0_W, c0_b, neigh, h0);

    k_stats<8><<<64, 256, 0, stream>>>(h0, NV2, st3);
    k_onering<8, 8><<<(NV2 + 255) / 256, 256, 0, stream>>>(
        h0, st3, NV2, bn1g, bn1b, c1_W, c1_b, neigh, h1);

    k_stats<8><<<64, 256, 0, stream>>>(h1, NV2, st4);
    k_onering<8, 2><<<(NV2 + 255) / 256, 256, 0, stream>>>(
        h1, st4, NV2, bn2g, bn2b, c2_W, c2_b, neigh, (float*)d_out);
}

// Round 4
// 110.745 us; speedup vs baseline: 1.0232x; 1.0232x over previous
//
#include <hip/hip_runtime.h>
#include <hip/hip_bf16.h>

// Sizes (static, from reference)
#define NSUB 65536
#define NV0 10242
#define NV1 40962
#define NV2 163842
#define EPSV 1e-5f
#define SPLITK 16
#define SLICE (NSUB / SPLITK)   // 4096

// ---------------------------------------------------------------------------
// Init: y1 = bias (gemv1 accumulates on top via atomics), stats accum = 0
__global__ void k_init(const float* __restrict__ bs, float* __restrict__ y1,
                       float* __restrict__ st) {
    int i = threadIdx.x;
    if (i < 256) y1[i] = bs[i];
    if (i < 50) st[i] = 0.f;
}

// ---------------------------------------------------------------------------
// y1[o] += sub_id[slice] . W_sub[o, slice]  (split-K, 4096 blocks)
__global__ __launch_bounds__(256) void k_gemv1(const float* __restrict__ sub,
                                               const float* __restrict__ Ws,
                                               float* __restrict__ y1) {
    int task = blockIdx.x;            // 256 outputs x 16 slices
    int o = task >> 4;
    int s = task & (SPLITK - 1);
    const float* row = Ws + (size_t)o * NSUB + s * SLICE;
    const float* sb  = sub + s * SLICE;
    int t = threadIdx.x;
    float a0 = 0.f, a1 = 0.f;
    // SLICE=4096 floats: 256 threads * float4 = 1024/pass -> 4 passes, 2 accs
#pragma unroll
    for (int p = 0; p < 4; p += 2) {
        int i0 = (p * 256 + t) * 4;
        int i1 = ((p + 1) * 256 + t) * 4;
        float4 x0 = *(const float4*)(sb + i0);
        float4 w0 = *(const float4*)(row + i0);
        float4 x1 = *(const float4*)(sb + i1);
        float4 w1 = *(const float4*)(row + i1);
        a0 += x0.x * w0.x + x0.y * w0.y + x0.z * w0.z + x0.w * w0.w;
        a1 += x1.x * w1.x + x1.y * w1.y + x1.z * w1.z + x1.w * w1.w;
    }
    float acc = a0 + a1;
#pragma unroll
    for (int off = 32; off > 0; off >>= 1) acc += __shfl_down(acc, off, 64);
    __shared__ float red[4];
    int wv = t >> 6, ln = t & 63;
    if (ln == 0) red[wv] = acc;
    __syncthreads();
    if (t == 0) atomicAdd(&y1[o], red[0] + red[1] + red[2] + red[3]);
}

// ---------------------------------------------------------------------------
// x0[o] = y1[0:256] . W_fc[o, :] + b_fc[o], o < 30726. One wave per output.
__global__ __launch_bounds__(256) void k_gemv2(const float* __restrict__ y1,
                                               const float* __restrict__ Wf,
                                               const float* __restrict__ bfc,
                                               float* __restrict__ x0) {
    int o = blockIdx.x * 4 + (threadIdx.x >> 6);
    int ln = threadIdx.x & 63;
    if (o >= 3 * NV0) return;
    const float* row = Wf + (size_t)o * 256;
    float4 w4 = *(const float4*)(row + ln * 4);
    float4 yv = *(const float4*)(y1 + ln * 4);
    float acc = w4.x * yv.x + w4.y * yv.y + w4.z * yv.z + w4.w * yv.w;
#pragma unroll
    for (int off = 32; off > 0; off >>= 1) acc += __shfl_down(acc, off, 64);
    if (ln == 0) x0[o] = acc + bfc[o];
}

// ---------------------------------------------------------------------------
// Per-channel sum and sum-of-squares of x [n, C] -> sums[0:C]=S1, sums[C:2C]=S2
template <int C>
__global__ __launch_bounds__(256) void k_stats(const float* __restrict__ x, int n,
                                               float* __restrict__ sums) {
    float s[C], q[C];
#pragma unroll
    for (int c = 0; c < C; ++c) { s[c] = 0.f; q[c] = 0.f; }
    for (int v = blockIdx.x * 256 + threadIdx.x; v < n; v += gridDim.x * 256) {
#pragma unroll
        for (int c = 0; c < C; ++c) {
            float t = x[(size_t)v * C + c];
            s[c] += t; q[c] += t * t;
        }
    }
#pragma unroll
    for (int c = 0; c < C; ++c) {
#pragma unroll
        for (int off = 32; off > 0; off >>= 1) {
            s[c] += __shfl_down(s[c], off, 64);
            q[c] += __shfl_down(q[c], off, 64);
        }
    }
    __shared__ float ls[4][2 * C];
    int wv = threadIdx.x >> 6, ln = threadIdx.x & 63;
    if (ln == 0) {
#pragma unroll
        for (int c = 0; c < C; ++c) { ls[wv][c] = s[c]; ls[wv][C + c] = q[c]; }
    }
    __syncthreads();
    if (threadIdx.x < 2 * C) {
        float t = ls[0][threadIdx.x] + ls[1][threadIdx.x] +
                  ls[2][threadIdx.x] + ls[3][threadIdx.x];
        atomicAdd(&sums[threadIdx.x], t);
    }
}

// ---------------------------------------------------------------------------
// upconv: xin [nIn,3] --bn,lrelu--> linear(3->21) viewed [nIn*7,3],
// then gather: v<nIn: u[top[v]]; else interleaved mean of u[down[2i]],u[down[2i+1]]
__global__ __launch_bounds__(256) void k_upconv(const float* __restrict__ xin, int nIn, int nOut,
                                                const float* __restrict__ sums,
                                                const float* __restrict__ g, const float* __restrict__ b,
                                                const float* __restrict__ W, const float* __restrict__ bias,
                                                const int* __restrict__ top, const int* __restrict__ down,
                                                float* __restrict__ xout) {
    __shared__ float sW[63], sB[21], sc[3], sh[3];
    int t = threadIdx.x;
    if (t < 63) sW[t] = W[t];
    if (t < 21) sB[t] = bias[t];
    if (t < 3) {
        float n = (float)nIn;
        float m = sums[t] / n;
        float var = sums[3 + t] / n - m * m;
        float rs = rsqrtf(var + EPSV);
        float scale = rs * g[t];
        sc[t] = scale;
        sh[t] = b[t] - m * scale;
    }
    __syncthreads();
    int v = blockIdx.x * 256 + t;
    if (v >= nOut) return;

    auto uval = [&](int idx, float* o3) {
        int src = idx / 7;
        int j = idx - src * 7;
        float a0 = xin[src * 3 + 0] * sc[0] + sh[0]; a0 = a0 > 0.f ? a0 : 0.2f * a0;
        float a1 = xin[src * 3 + 1] * sc[1] + sh[1]; a1 = a1 > 0.f ? a1 : 0.2f * a1;
        float a2 = xin[src * 3 + 2] * sc[2] + sh[2]; a2 = a2 > 0.f ? a2 : 0.2f * a2;
#pragma unroll
        for (int c = 0; c < 3; ++c) {
            int r = j * 3 + c;
            o3[c] = sB[r] + a0 * sW[r * 3 + 0] + a1 * sW[r * 3 + 1] + a2 * sW[r * 3 + 2];
        }
    };

    if (v < nIn) {
        float o3[3];
        uval(top[v], o3);
        xout[(size_t)v * 3 + 0] = o3[0];
        xout[(size_t)v * 3 + 1] = o3[1];
        xout[(size_t)v * 3 + 2] = o3[2];
    } else {
        int i = v - nIn;
        float a[3], bb[3];
        uval(down[2 * i], a);
        uval(down[2 * i + 1], bb);
        // x[down].reshape(-1, 3, 2).mean(2): interleaved pairing
        xout[(size_t)v * 3 + 0] = 0.5f * (a[0] + a[1]);
        xout[(size_t)v * 3 + 1] = 0.5f * (a[2] + bb[0]);
        xout[(size_t)v * 3 + 2] = 0.5f * (bb[1] + bb[2]);
    }
}

// ---------------------------------------------------------------------------
// one-ring conv: gather 7 neighbors of lrelu(bn(xin)), apply [COUT, 7*CIN] linear
template <int CIN, int COUT>
__global__ __launch_bounds__(256) void k_onering(const float* __restrict__ xin,
                                                 const float* __restrict__ sums, int n,
                                                 const float* __restrict__ g, const float* __restrict__ b,
                                                 const float* __restrict__ W, const float* __restrict__ bias,
                                                 const int* __restrict__ neigh,
                                                 float* __restrict__ out) {
    __shared__ float sW[COUT * 7 * CIN], sB[COUT], sc[CIN], sh[CIN];
    int t = threadIdx.x;
    for (int i = t; i < COUT * 7 * CIN; i += 256) sW[i] = W[i];
    if (t < COUT) sB[t] = bias[t];
    if (t < CIN) {
        float nn = (float)n;
        float m = sums[t] / nn;
        float var = sums[CIN + t] / nn - m * m;
        float rs = rsqrtf(var + EPSV);
        float scale = rs * g[t];
        sc[t] = scale;
        sh[t] = b[t] - m * scale;
    }
    __syncthreads();
    int v = blockIdx.x * 256 + t;
    if (v >= n) return;

    float acc[COUT];
#pragma unroll
    for (int c = 0; c < COUT; ++c) acc[c] = sB[c];
#pragma unroll
    for (int j = 0; j < 7; ++j) {
        int nb = neigh[v * 7 + j];
        float tv[CIN];
#pragma unroll
        for (int k = 0; k < CIN; ++k) {
            float x = xin[(size_t)nb * CIN + k] * sc[k] + sh[k];
            tv[k] = x > 0.f ? x : 0.2f * x;
        }
#pragma unroll
        for (int c = 0; c < COUT; ++c) {
            float a = acc[c];
#pragma unroll
            for (int k = 0; k < CIN; ++k) a += tv[k] * sW[c * 7 * CIN + j * CIN + k];
            acc[c] = a;
        }
    }
#pragma unroll
    for (int c = 0; c < COUT; ++c) out[(size_t)v * COUT + c] = acc[c];
}

// ---------------------------------------------------------------------------
extern "C" void kernel_launch(void* const* d_in, const int* in_sizes, int n_in,
                              void* d_out, int out_size, void* d_ws, size_t ws_size,
                              hipStream_t stream) {
    const float* sub_id = (const float*)d_in[0];
    const float* W_sub  = (const float*)d_in[1];
    const float* b_sub  = (const float*)d_in[2];
    const float* W_fc   = (const float*)d_in[3];
    const float* b_fc   = (const float*)d_in[4];
    const float* bn_u0g = (const float*)d_in[5];
    const float* bn_u0b = (const float*)d_in[6];
    const float* up0_W  = (const float*)d_in[7];
    const float* up0_b  = (const float*)d_in[8];
    const float* bn_u1g = (const float*)d_in[9];
    const float* bn_u1b = (const float*)d_in[10];
    const float* up1_W  = (const float*)d_in[11];
    const float* up1_b  = (const float*)d_in[12];
    const float* bn0g   = (const float*)d_in[13];
    const float* bn0b   = (const float*)d_in[14];
    const float* c0_W   = (const float*)d_in[15];
    const float* c0_b   = (const float*)d_in[16];
    const float* bn1g   = (const float*)d_in[17];
    const float* bn1b   = (const float*)d_in[18];
    const float* c1_W   = (const float*)d_in[19];
    const float* c1_b   = (const float*)d_in[20];
    const float* bn2g   = (const float*)d_in[21];
    const float* bn2b   = (const float*)d_in[22];
    const float* c2_W   = (const float*)d_in[23];
    const float* c2_b   = (const float*)d_in[24];
    const int* neigh  = (const int*)d_in[25];
    const int* top0   = (const int*)d_in[26];
    const int* down0  = (const int*)d_in[27];
    const int* top1   = (const int*)d_in[28];
    const int* down1  = (const int*)d_in[29];

    float* ws = (float*)d_ws;
    float* y1 = ws;                       // 256
    float* x0 = y1 + 256;                 // 30726
    float* xA = x0 + 30726;               // 122886
    float* xB = xA + 122886;              // 491526
    float* h0 = xB + 491526;              // 1310736
    float* h1 = h0 + 1310736;             // 1310736
    float* st = h1 + 1310736;             // 50 floats of stats accumulators
    float* st0 = st;        // x0 stats  [6]
    float* st1 = st + 6;    // xA stats  [6]
    float* st2 = st + 12;   // xB stats  [6]
    float* st3 = st + 18;   // h0 stats  [16]
    float* st4 = st + 34;   // h1 stats  [16]

    k_init<<<1, 256, 0, stream>>>(b_sub, y1, st);

    k_gemv1<<<256 * SPLITK, 256, 0, stream>>>(sub_id, W_sub, y1);
    k_gemv2<<<(3 * NV0 + 3) / 4, 256, 0, stream>>>(y1, W_fc, b_fc, x0);

    k_stats<3><<<64, 256, 0, stream>>>(x0, NV0, st0);
    k_upconv<<<(NV1 + 255) / 256, 256, 0, stream>>>(x0, NV0, NV1, st0,
                                                    bn_u0g, bn_u0b, up0_W, up0_b,
                                                    top0, down0, xA);
    k_stats<3><<<64, 256, 0, stream>>>(xA, NV1, st1);
    k_upconv<<<(NV2 + 255) / 256, 256, 0, stream>>>(xA, NV1, NV2, st1,
                                                    bn_u1g, bn_u1b, up1_W, up1_b,
                                                    top1, down1, xB);

    k_stats<3><<<64, 256, 0, stream>>>(xB, NV2, st2);
    k_onering<3, 8><<<(NV2 + 255) / 256, 256, 0, stream>>>(
        xB, st2, NV2, bn0g, bn0b, c0_W, c0_b, neigh, h0);

    k_stats<8><<<64, 256, 0, stream>>>(h0, NV2, st3);
    k_onering<8, 8><<<(NV2 + 255) / 256, 256, 0, stream>>>(
        h0, st3, NV2, bn1g, bn1b, c1_W, c1_b, neigh, h1);

    k_stats<8><<<64, 256, 0, stream>>>(h1, NV2, st4);
    k_onering<8, 2><<<(NV2 + 255) / 256, 256, 0, stream>>>(
        h1, st4, NV2, bn2g, bn2b, c2_W, c2_b, neigh, (float*)d_out);
}